// Round 13
// baseline (347.298 us; speedup 1.0000x reference)
//
#include <hip/hip_runtime.h>

// Bidirectional LSTM, B=256, T=1024, V=6, D=64, U=64; out = last-step
// concat(h_f, h_b) @ Wd + bd, shape (B,1).
// Reductions: backward dir = ONE step from h0=0 (Wr_b dead); V=6 -> xproj is
// a 6x256 table; mask = 6-bit scalar.
// R8: h-reads-first (310us). R11: pad -> conflicts insensitive (benign 2-way).
// R12: f16 h exchange (2x ds_read_b128) + v_dot2 MACs (296us) -- but VALU
//      cyc/step ROSE: v_dot2_f32_f16 is HALF-RATE on gfx950; the win was
//      purely the halved h payload.
// R13: full-rate packed f16 MACs: per gate 1 v_pk_mul_f16 + 7 v_pk_fma_f16
//      (f16 accumulate, chain depth 8) + one dot2(acc,{1,1}) f32 fold.
//      MAC issue ~128 -> ~80 cyc. f16 accumulation adds ~2e-4/gate rms;
//      est. output err well under the 2.37e-3 threshold.

constexpr int kB = 256;
constexpr int kT = 1024;
constexpr int kV = 6;
constexpr int kD = 64;
constexpr int kU = 64;
constexpr int kG = 256; // 4*U gate columns

#define LOG2E 1.44269504f

typedef _Float16 v2h __attribute__((ext_vector_type(2)));

template <int CTRL>
__device__ __forceinline__ float dppf(float x) {
    return __int_as_float(
        __builtin_amdgcn_mov_dpp(__float_as_int(x), CTRL, 0xF, 0xF, true));
}
constexpr int kXor1 = 0xB1; // quad_perm(1,0,3,2)
constexpr int kXor2 = 0x4E; // quad_perm(2,3,0,1)
constexpr int kBc0 = 0x00, kBc1 = 0x55, kBc2 = 0xAA, kBc3 = 0xFF;

__device__ __forceinline__ float fast_rcp(float x) { return __builtin_amdgcn_rcpf(x); }
__device__ __forceinline__ float exp2_f(float x)   { return __builtin_amdgcn_exp2f(x); }
__device__ __forceinline__ float sig_f(float z)  { return fast_rcp(1.0f + exp2_f(-LOG2E * z)); }
__device__ __forceinline__ float tanh_f(float z) { return 2.0f * fast_rcp(1.0f + exp2_f(-2.0f * LOG2E * z)) - 1.0f; }

__device__ __forceinline__ v2h as_v2h(float x) { return __builtin_bit_cast(v2h, x); }

__global__ __launch_bounds__(256, 1) void bilstm_last_kernel(
    const int*   __restrict__ tokens, // (B,T)
    const float* __restrict__ emb,    // (6,64)
    const float* __restrict__ Wk_f,   // (64,256)
    const float* __restrict__ Wr_f,   // (64,256)
    const float* __restrict__ b_f,    // (256)
    const float* __restrict__ Wk_b,   // (64,256)
    const float* __restrict__ b_b,    // (256)
    const float* __restrict__ Wd,     // (128)
    const float* __restrict__ bd,     // (1)
    float*       __restrict__ out)    // (B)
{
    __shared__ float s_emb[kV * kD];
    __shared__ float s_projP[kV * kG];              // PERMUTED xproj_f table
    __shared__ int   s_tok[kT];
    __shared__ _Float16 __align__(16) s_hh[2][kU];  // double-buffered h (f16)
    __shared__ float s_act[kG];                     // scratch (bwd step + epilogue)

    const int b   = blockIdx.x;
    const int tid = threadIdx.x;
    const int l   = tid & 63;       // lane in wave
    const int wv  = tid >> 6;       // wave id 0..3
    const int s   = l & 3;          // h-slice AND owned gate (0..3 = i,f,g,o)
    const int k   = l >> 2;         // 0..15
    const int u   = wv * 16 + k;    // unit owned by this quad

    // ---- stage emb + tokens ----
    for (int i = tid; i < kV * kD; i += 256) s_emb[i] = emb[i];
    ((int4*)s_tok)[tid] = ((const int4*)(tokens + b * kT))[tid];
    if (tid < kU) { s_hh[0][tid] = (_Float16)0.f; s_hh[1][tid] = (_Float16)0.f; }
    __syncthreads();

    // ---- 6-bit mask, scalarized: bit v = any(emb[v][:] != 0) ----
    unsigned int mbv = 0;
#pragma unroll
    for (int v = 0; v < kV; ++v) {
        const unsigned long long bb = __ballot(s_emb[v * kD + l] != 0.0f);
        mbv |= (bb != 0ull) ? (1u << v) : 0u;
    }
    const unsigned int smb = __builtin_amdgcn_readfirstlane(mbv);

    const int tokL = s_tok[kT - 1];

    // ---- proj table (coalesced global reads per column tid), stored PERMUTED
    // so lane q of the step loop reads proj[v][ (q&3)*64 + u(q) ] at
    // s_projP[v*256+q].
    float a0 = b_f[tid], a1 = a0, a2 = a0, a3 = a0, a4 = a0, a5 = a0;
    float accb = b_b[tid];
    for (int d = 0; d < kD; ++d) {
        const float wkf = Wk_f[d * kG + tid];
        const float wkb = Wk_b[d * kG + tid];
        a0 = fmaf(s_emb[0 * kD + d], wkf, a0);
        a1 = fmaf(s_emb[1 * kD + d], wkf, a1);
        a2 = fmaf(s_emb[2 * kD + d], wkf, a2);
        a3 = fmaf(s_emb[3 * kD + d], wkf, a3);
        a4 = fmaf(s_emb[4 * kD + d], wkf, a4);
        a5 = fmaf(s_emb[5 * kD + d], wkf, a5);
        accb = fmaf(s_emb[tokL * kD + d], wkb, accb);
    }
    {   // inverse perm: lane q wanting column 'tid' is q = w0*64 + k0*4 + g0
        const int g0 = tid >> 6, u0 = tid & 63, w0 = u0 >> 4, k0 = u0 & 15;
        const int q = w0 * 64 + k0 * 4 + g0;
        s_projP[0 * kG + q] = a0;
        s_projP[1 * kG + q] = a1;
        s_projP[2 * kG + q] = a2;
        s_projP[3 * kG + q] = a3;
        s_projP[4 * kG + q] = a4;
        s_projP[5 * kG + q] = a5;
    }

    // ---- backward single step: z = xproj_b only (h0=0, c0=0 -> f dead) ----
    float ab;
    if (tid < 128)      ab = sig_f(accb);
    else if (tid < 192) ab = tanh_f(accb);
    else                ab = sig_f(accb);
    s_act[tid] = ab;
    __syncthreads();
    float hb_val = 0.0f;
    if (tid < kU) {
        const float cb = s_act[tid] * s_act[2 * kU + tid];
        const float hb = s_act[3 * kU + tid] * tanh_f(cb);
        hb_val = ((smb >> tokL) & 1) ? hb : 0.0f;
    }

    // ---- recurrent weights: f16 pairs, 8 v2h per gate (32 VGPRs total) ----
#define DECLH(g, p)                                                         \
    v2h wh##g##_##p;                                                        \
    wh##g##_##p.x = (_Float16)Wr_f[(16 * s + 2 * p + 0) * kG + (g * 64 + u)]; \
    wh##g##_##p.y = (_Float16)Wr_f[(16 * s + 2 * p + 1) * kG + (g * 64 + u)];
    DECLH(0,0) DECLH(0,1) DECLH(0,2) DECLH(0,3) DECLH(0,4) DECLH(0,5) DECLH(0,6) DECLH(0,7)
    DECLH(1,0) DECLH(1,1) DECLH(1,2) DECLH(1,3) DECLH(1,4) DECLH(1,5) DECLH(1,6) DECLH(1,7)
    DECLH(2,0) DECLH(2,1) DECLH(2,2) DECLH(2,3) DECLH(2,4) DECLH(2,5) DECLH(2,6) DECLH(2,7)
    DECLH(3,0) DECLH(3,1) DECLH(3,2) DECLH(3,3) DECLH(3,4) DECLH(3,5) DECLH(3,6) DECLH(3,7)
#undef DECLH

    const v2h kOnes = {(_Float16)1.f, (_Float16)1.f};

    // per-lane activation constants: gate s==2 is tanh, others sigmoid
    const bool  isg    = (s == 2);
    const float aScale = isg ? -2.0f * LOG2E : -LOG2E;
    const float aMul   = isg ? 2.0f : 1.0f;
    const float aAdd   = isg ? -1.0f : 0.0f;

    float c = 0.0f, hreg = 0.0f;
    __syncthreads();   // projP + s_hh init visible

    // ---- scalar token pipeline, depth 2 (through LDS, as in R6/R8) ----
    int stok0 = __builtin_amdgcn_readfirstlane(s_tok[0]);
    float zcur = s_projP[stok0 * kG + tid];   // own-gate proj for this lane
    int   mskc = (smb >> stok0) & 1;          // scalar
    int   stokA = __builtin_amdgcn_readfirstlane(s_tok[1]);

    // per gate: 1 pk_mul + 7 pk_fma (f16 acc, full-rate) + dot2 fold to f32
#define DOTG(g)                                                               \
        v2h q##g = H0 * wh##g##_0;                                            \
        q##g = __builtin_elementwise_fma(H1, wh##g##_1, q##g);                \
        q##g = __builtin_elementwise_fma(H2, wh##g##_2, q##g);                \
        q##g = __builtin_elementwise_fma(H3, wh##g##_3, q##g);                \
        q##g = __builtin_elementwise_fma(H4, wh##g##_4, q##g);                \
        q##g = __builtin_elementwise_fma(H5, wh##g##_5, q##g);                \
        q##g = __builtin_elementwise_fma(H6, wh##g##_6, q##g);                \
        q##g = __builtin_elementwise_fma(H7, wh##g##_7, q##g);                \
        float p##g = __builtin_amdgcn_fdot2(q##g, kOnes, 0.0f, false);

#define STEP(RP, WP, TT)                                                      \
    {                                                                         \
        /* h reads FIRST; slice s = 16 halves = 32B = 2x b128 */              \
        const float4* hp = (const float4*)s_hh[RP];                           \
        const float4 hv0 = hp[s * 2 + 0];                                     \
        const float4 hv1 = hp[s * 2 + 1];                                     \
        /* prefetches behind h in the queue; consumed next step */            \
        const int   vtokB = s_tok[((TT) + 2) & (kT - 1)];                     \
        const float znext = s_projP[stokA * kG + tid];                        \
        const int   mskn  = (int)((smb >> stokA) & 1);                        \
        const v2h H0 = as_v2h(hv0.x), H1 = as_v2h(hv0.y);                     \
        const v2h H2 = as_v2h(hv0.z), H3 = as_v2h(hv0.w);                     \
        const v2h H4 = as_v2h(hv1.x), H5 = as_v2h(hv1.y);                     \
        const v2h H6 = as_v2h(hv1.z), H7 = as_v2h(hv1.w);                     \
        DOTG(0) DOTG(1) DOTG(2) DOTG(3)                                       \
        /* round 1: 2-lane sums over xor1 pairs, all gates */                 \
        p0 += dppf<kXor1>(p0); p1 += dppf<kXor1>(p1);                         \
        p2 += dppf<kXor1>(p2); p3 += dppf<kXor1>(p3);                         \
        /* select own pair-gate (xor2 partner has same s&1 -> gate-uniform) */\
        float X = (s & 1) ? p1 : p0;                                          \
        float Y = (s & 1) ? p3 : p2;                                          \
        X += dppf<kXor2>(X); Y += dppf<kXor2>(Y);                             \
        const float z = ((s & 2) ? Y : X) + zcur;                             \
        /* one activation per lane (own gate) */                              \
        const float e = exp2_f(z * aScale);                                   \
        const float r = fast_rcp(1.0f + e);                                   \
        const float a = fmaf(r, aMul, aAdd);                                  \
        /* quad broadcasts: gate q lives in lane q of the quad */             \
        const float ai = dppf<kBc0>(a);                                       \
        const float af = dppf<kBc1>(a);                                       \
        const float ag = dppf<kBc2>(a);                                       \
        const float ao = dppf<kBc3>(a);                                       \
        const float cn = fmaf(af, c, ai * ag);                                \
        const float hn = ao * tanh_f(cn);                                     \
        if (mskc) { c = cn; hreg = hn; }   /* uniform branch */               \
        if (s == 0) s_hh[WP][u] = (_Float16)hreg;                             \
        __syncthreads();                                                      \
        zcur = znext; mskc = mskn;                                            \
        stokA = __builtin_amdgcn_readfirstlane(vtokB);                        \
    }

    for (int t = 0; t < kT; t += 2) {
        STEP(0, 1, t)
        STEP(1, 0, t + 1)
    }
#undef STEP
#undef DOTG

    // ---- epilogue: owner lanes publish exact f32 h, then reduce ----
    if (s == 0) s_act[u] = hreg;          // full-precision final h
    __syncthreads();
    if (tid < kU) {
        float v = s_act[tid] * Wd[tid] + hb_val * Wd[kU + tid];
#pragma unroll
        for (int off = 32; off > 0; off >>= 1) v += __shfl_down(v, off, 64);
        if (tid == 0) out[b] = v + bd[0];
    }
}

extern "C" void kernel_launch(void* const* d_in, const int* in_sizes, int n_in,
                              void* d_out, int out_size, void* d_ws, size_t ws_size,
                              hipStream_t stream) {
    const int*   tokens = (const int*)d_in[0];
    const float* emb    = (const float*)d_in[1];
    const float* Wk_f   = (const float*)d_in[2];
    const float* Wr_f   = (const float*)d_in[3];
    const float* b_f    = (const float*)d_in[4];
    const float* Wk_b   = (const float*)d_in[5];
    // d_in[6] = Wr_b: unused (backward runs one step from h0=0)
    const float* b_b    = (const float*)d_in[7];
    const float* Wd     = (const float*)d_in[8];
    const float* bd     = (const float*)d_in[9];
    float* out = (float*)d_out;

    bilstm_last_kernel<<<kB, 256, 0, stream>>>(
        tokens, emb, Wk_f, Wr_f, b_f, Wk_b, b_b, Wd, bd, out);
}